// Round 1
// baseline (127.954 us; speedup 1.0000x reference)
//
#include <hip/hip_runtime.h>

#define BATCH 8
#define HDIM  512
#define WDIM  512
#define PLANE (HDIM * WDIM)

// Only pack rows/cols >= 255 are ever gathered (ix = i*256/511 + 255.5 + 256*sigmoid > 255.5).
// Pack rows 254..511 (= 129 row-pairs) — quadrant repack, 2x fewer bytes, 4x fewer threads.
#define PACK_ROW0   254
#define PACK_PAIRS  129
#define DEAD_ADDR   ((255 << 9) + 255)   // packed texel; weight is 0 whenever used

typedef _Float16 half2v __attribute__((ext_vector_type(2)));
typedef _Float16 half8v __attribute__((ext_vector_type(8)));
typedef float    f2v    __attribute__((ext_vector_type(2)));

// two adjacent texels (x0,x0+1), each (c0,c1),(c2,0) as half2 pairs; 16B
struct __align__(8) HQuad { half2v p0, p1, p2, p3; };

#if __has_builtin(__builtin_amdgcn_fdot2)
#define FDOT2(a, b, c) __builtin_amdgcn_fdot2((a), (b), (c), false)
#else
#define FDOT2(a, b, c) fmaf((float)(a).x, (float)(b).x, fmaf((float)(a).y, (float)(b).y, (c)))
#endif

#if __has_builtin(__builtin_amdgcn_exp2f)
#define EXP2F(x) __builtin_amdgcn_exp2f(x)
#else
#define EXP2F(x) exp2f(x)
#endif

// ---------- quadrant repack: rows 254..511 only; XCD-swizzled (img = blk&7) ----------
// grid = 8 * PACK_PAIRS blocks; block (b, r) packs rows 254+2r, 255+2r (1024 px, 4 px/thread)
__global__ __launch_bounds__(256) void repack_quad(
    const float* __restrict__ x,   // [B,3,H,W]
    half8v* __restrict__ xp)       // [B,H,W] half4, only rows >=254 filled
{
    int b = blockIdx.x & 7;
    int r = blockIdx.x >> 3;                       // [0, PACK_PAIRS)
    int pix = ((PACK_ROW0 + 2 * r) << 9) + threadIdx.x * 4;
    const float* xb = x + (size_t)b * 3 * PLANE;
    float4 a0 = *(const float4*)(xb + pix);
    float4 a1 = *(const float4*)(xb + PLANE + pix);
    float4 a2 = *(const float4*)(xb + 2 * PLANE + pix);
    half8v o0, o1;
    o0[0] = (_Float16)a0.x; o0[1] = (_Float16)a1.x; o0[2] = (_Float16)a2.x; o0[3] = (_Float16)0.f;
    o0[4] = (_Float16)a0.y; o0[5] = (_Float16)a1.y; o0[6] = (_Float16)a2.y; o0[7] = (_Float16)0.f;
    o1[0] = (_Float16)a0.z; o1[1] = (_Float16)a1.z; o1[2] = (_Float16)a2.z; o1[3] = (_Float16)0.f;
    o1[4] = (_Float16)a0.w; o1[5] = (_Float16)a1.w; o1[6] = (_Float16)a2.w; o1[7] = (_Float16)0.f;
    size_t base = (size_t)b * (PLANE / 2) + (size_t)(pix >> 1);
    xp[base]     = o0;
    xp[base + 1] = o1;
}

// ---------- main v10: 2 px/thread; shared conv columns; 20 gathers pinned in flight ----------
// grid = 8 images * 512 rows; thread t handles pixels (i, 2t) and (i, 2t+1)
__global__ __launch_bounds__(256) void seesaw_v10(
    const float* __restrict__ x,     // [B,3,H,W] fp32 (conv + mirror)
    const char* __restrict__ xpack,  // [B,H,W] half4 as bytes
    const float* __restrict__ w1, const float* __restrict__ b1,
    const float* __restrict__ w2, const float* __restrict__ b2,
    float* __restrict__ out)
{
    int t  = threadIdx.x;
    int b  = blockIdx.x & 7;          // image -> XCD locality
    int i  = blockIdx.x >> 3;         // SCALAR row (block covers a full row)
    int j0 = t << 1;                  // even col; px0 = j0, px1 = j0+1

    const float* xb = x + (size_t)b * 3 * PLANE;
    const char*  hb = xpack + ((size_t)b << 21);   // PLANE * 8 bytes

    // ---- conv inputs for the pixel pair: per rowchan cols {j0-1, j0, j0+1, j0+2} ----
    int cm = j0 - 1; if (cm < 0) cm = 0;
    int cp = j0 + 2; if (cp > 511) cp = 511;
    bool jlo = (t == 0), jhi = (t == 255);

    float vm[9], va[9], vb9[9], vp9[9];   // index r = c*3 + di
    if (i >= 1 && i <= 510) {             // interior rows (uniform branch)
#pragma unroll
        for (int di = 0; di < 3; di++) {
            const float* row = xb + ((i + di - 1) << 9);
#pragma unroll
            for (int c = 0; c < 3; c++) {
                const float* rc = row + c * PLANE;
                float m = rc[cm]; if (jlo) m = 0.f;
                f2v  mid = *(const f2v*)(rc + j0);     // 8B aligned (j0 even)
                float p = rc[cp]; if (jhi) p = 0.f;
                int r = c * 3 + di;
                vm[r] = m; va[r] = mid[0]; vb9[r] = mid[1]; vp9[r] = p;
            }
        }
    } else {                               // y-edge rows (16/4096 blocks)
#pragma unroll
        for (int di = 0; di < 3; di++) {
            int y = i + di - 1;
            bool yv = (unsigned)y < (unsigned)HDIM;
            const float* row = xb + ((yv ? y : 0) << 9);
#pragma unroll
            for (int c = 0; c < 3; c++) {
                const float* rc = row + c * PLANE;
                float m = rc[cm]; if (jlo || !yv) m = 0.f;
                f2v  mid = *(const f2v*)(rc + j0);
                float p = rc[cp]; if (jhi || !yv) p = 0.f;
                float m0 = yv ? mid[0] : 0.f;
                float m1 = yv ? mid[1] : 0.f;
                int r = c * 3 + di;
                vm[r] = m; va[r] = m0; vb9[r] = m1; vp9[r] = p;
            }
        }
    }
    __builtin_amdgcn_sched_barrier(0);   // all 27 conv loads issued before math

    // ---- build tap arrays (register renames) ----
    float tap0[27], tap1[27];   // k = c*9 + di*3 + dj
#pragma unroll
    for (int c = 0; c < 3; c++)
#pragma unroll
        for (int di = 0; di < 3; di++) {
            int r = c * 3 + di, k = c * 9 + di * 3;
            tap0[k]     = vm[r];  tap0[k + 1] = va[r];  tap0[k + 2] = vb9[r];
            tap1[k]     = va[r];  tap1[k + 1] = vb9[r]; tap1[k + 2] = vp9[r];
        }

    // ---- 27-tap dot via packed f32 FMA + sigmoid (pre-scaled by 256) ----
    const float NLOG2E = -1.44269504f;
    auto conv8 = [&](const float* tap, float* s2) {
        f2v V[13];
#pragma unroll
        for (int k = 0; k < 13; k++) { V[k][0] = tap[2 * k]; V[k][1] = tap[2 * k + 1]; }
#pragma unroll
        for (int e = 0; e < 8; e++) {
            const float* we = w1 + e * 27;
            f2v a2; a2[0] = b1[e]; a2[1] = 0.f;
#pragma unroll
            for (int k = 0; k < 13; k++) {
                f2v ww; ww[0] = we[2 * k]; ww[1] = we[2 * k + 1];
                a2 = __builtin_elementwise_fma(V[k], ww, a2);
            }
            float acc = a2[0] + a2[1] + tap[26] * we[26];
            s2[e] = 256.0f * __builtin_amdgcn_rcpf(1.0f + EXP2F(acc * NLOG2E));
        }
    };
    float s0[8], s1[8];
    conv8(tap0, s0);
    conv8(tap1, s1);

    // ---- w2 rows packed to half2 (wave-uniform) ----
    half2v w2a[5], w2b[5];
#pragma unroll
    for (int q = 0; q < 5; q++) {
        w2a[q][0] = (_Float16)w2[q * 3];
        w2a[q][1] = (_Float16)w2[q * 3 + 1];
        w2b[q][0] = (_Float16)w2[q * 3 + 2];
        w2b[q][1] = (_Float16)0.f;
    }

    const float k511 = 256.0f / 511.0f;
    float fxb = fmaf((float)i, k511, 255.5f);   // feeds gx (reference axis swap)
    float fy0 = fmaf((float)j0, k511, 255.5f);
    float fy1 = fy0 + k511;

    // ---- gather phase 1: addresses + weights (integer dead tests) ----
    int   adrA[5][2], adrB[5][2];
    float wXA[5][2], wYA[5][2], wXB[5][2], wYB[5][2];
    auto phase1 = [&](const float* s2, float fyb, int (&adr)[5][2],
                      float (&wX)[5][2], float (&wY)[5][2]) {
#pragma unroll
        for (int q = 0; q < 5; q++) {
            float ixf = (q < 4) ? (fxb + s2[2 * q])     : fxb;
            float iyf = (q < 4) ? (fyb + s2[2 * q + 1]) : fyb;
            int ix0 = (int)ixf, iy0 = (int)iyf;         // positive: trunc == floor; >= 255
            float wx1 = ixf - (float)ix0, wy1 = iyf - (float)iy0;
            float wx0 = 1.f - wx1,        wy0 = 1.f - wy1;
            bool xin0 = (ix0 <= 511), xin1 = (ix0 <= 510);
            bool yin0 = (iy0 <= 511), yin1 = (iy0 <= 510);
            wX[q][0] = xin0 ? wx0 : 0.f;
            wX[q][1] = xin1 ? wx1 : 0.f;
            wY[q][0] = yin0 ? wy0 : 0.f;
            wY[q][1] = yin1 ? wy1 : 0.f;
            int x0c = min(ix0, 511);
            int a0  = (min(iy0, 511) << 9) + x0c;
            // wy0>0 & wx0>0 strictly, so dead tests reduce to integer range checks
            adr[q][0] = (yin0 & xin0) ? a0        : DEAD_ADDR;
            adr[q][1] = (yin1 & xin0) ? a0 + 512  : DEAD_ADDR;
        }
    };

    // ---- gather phase 2: px0 addresses -> 10 loads, px1 addresses -> 10 loads ----
    phase1(s0, fy0, adrA, wXA, wYA);
    HQuad qA[5][2];
#pragma unroll
    for (int q = 0; q < 5; q++) {
        qA[q][0] = *(const HQuad*)(hb + ((size_t)adrA[q][0] << 3));
        qA[q][1] = *(const HQuad*)(hb + ((size_t)adrA[q][1] << 3));
    }
    phase1(s1, fy1, adrB, wXB, wYB);   // VALU overlaps px0 loads
    HQuad qB[5][2];
#pragma unroll
    for (int q = 0; q < 5; q++) {
        qB[q][0] = *(const HQuad*)(hb + ((size_t)adrB[q][0] << 3));
        qB[q][1] = *(const HQuad*)(hb + ((size_t)adrB[q][1] << 3));
    }
    __builtin_amdgcn_sched_barrier(0);   // pin all 20 gathers in flight before any use

    // ---- gather phase 3: fp16 dot per texel, bilinear combine ----
    float ogA[3] = {0.f, 0.f, 0.f}, ogB[3] = {0.f, 0.f, 0.f};
    auto phase3 = [&](HQuad (&qv)[5][2], float (&wX)[5][2], float (&wY)[5][2], float* og) {
#pragma unroll
        for (int q = 0; q < 5; q++) {
            int g = q / 3;              // 0,0,0,1,1
            float dl0 = FDOT2(qv[q][0].p0, w2a[q], FDOT2(qv[q][0].p1, w2b[q], 0.f));
            float dh0 = FDOT2(qv[q][0].p2, w2a[q], FDOT2(qv[q][0].p3, w2b[q], 0.f));
            float dl1 = FDOT2(qv[q][1].p0, w2a[q], FDOT2(qv[q][1].p1, w2b[q], 0.f));
            float dh1 = FDOT2(qv[q][1].p2, w2a[q], FDOT2(qv[q][1].p3, w2b[q], 0.f));
            float r0 = fmaf(dh0, wX[q][1], dl0 * wX[q][0]);
            float r1 = fmaf(dh1, wX[q][1], dl1 * wX[q][0]);
            og[g] = fmaf(r1, wY[q][1], fmaf(r0, wY[q][0], og[g]));
        }
    };
    phase3(qA, wXA, wYA, ogA);
    phase3(qB, wXB, wYB, ogB);

    // ---- mirror points p=5..8: only pixel (0,0) of each image contributes ----
    if ((i | j0) == 0) {
#pragma unroll
        for (int p = 5; p < 9; p++) {
            float ixf = fxb + 512.0f - s0[2 * (p - 5)];
            float iyf = fy0 + 512.0f - s0[2 * (p - 5) + 1];
            float ix0f = floorf(ixf), iy0f = floorf(iyf);
            float wx1 = ixf - ix0f, wy1 = iyf - iy0f;
            float wx0 = 1.f - wx1,  wy0 = 1.f - wy1;
            int ix0 = (int)ix0f, iy0 = (int)iy0f;
            float t0 = 0.f, t1 = 0.f, t2 = 0.f;
            for (int cy = 0; cy < 2; cy++) {
                int yc2 = iy0 + cy;
                if (yc2 < 0 || yc2 >= HDIM) continue;
                float wy = cy ? wy1 : wy0;
                for (int cx = 0; cx < 2; cx++) {
                    int xcc2 = ix0 + cx;
                    if (xcc2 < 0 || xcc2 >= WDIM) continue;
                    float wgt = wy * (cx ? wx1 : wx0);
                    int base = (yc2 << 9) + xcc2;
                    t0 = fmaf(xb[base],             wgt, t0);
                    t1 = fmaf(xb[PLANE + base],     wgt, t1);
                    t2 = fmaf(xb[2 * PLANE + base], wgt, t2);
                }
            }
            int g  = p / 3;
            int k0 = (p % 3) * 3;
            ogA[g] = fmaf(t0, w2[g * 9 + k0 + 0], ogA[g]);
            ogA[g] = fmaf(t1, w2[g * 9 + k0 + 1], ogA[g]);
            ogA[g] = fmaf(t2, w2[g * 9 + k0 + 2], ogA[g]);
        }
    }

    // ---- bias + relu + paired store ----
    size_t ob = (size_t)(b * 3) * PLANE + ((size_t)i << 9) + j0;
#pragma unroll
    for (int g = 0; g < 3; g++) {
        float u0 = ogA[g] + b2[g];
        float u1 = ogB[g] + b2[g];
        f2v st;
        st[0] = u0 > 0.f ? u0 : 0.f;
        st[1] = u1 > 0.f ? u1 : 0.f;
        *(f2v*)(out + ob + (size_t)g * PLANE) = st;
    }
}

// ---------- no-workspace fallback (round-1 style) ----------
__global__ __launch_bounds__(256) void seesaw_fused_v1(
    const float* __restrict__ x, const float* __restrict__ w1,
    const float* __restrict__ b1, const float* __restrict__ w2,
    const float* __restrict__ b2, float* __restrict__ out)
{
    int t = threadIdx.x;
    int gid = blockIdx.x * 256 + t;
    int j = gid & (WDIM - 1);
    int i = (gid >> 9) & (HDIM - 1);
    int b = gid >> 18;
    const float* xb = x + (size_t)b * 3 * PLANE;
    float acc[8];
#pragma unroll
    for (int e = 0; e < 8; e++) acc[e] = b1[e];
#pragma unroll
    for (int di = 0; di < 3; di++) {
        int y = i + di - 1;
        if (y < 0 || y >= HDIM) continue;
#pragma unroll
        for (int dj = 0; dj < 3; dj++) {
            int xc = j + dj - 1;
            if (xc < 0 || xc >= WDIM) continue;
            size_t base = (size_t)y * WDIM + xc;
#pragma unroll
            for (int c = 0; c < 3; c++) {
                float v = xb[(size_t)c * PLANE + base];
#pragma unroll
                for (int e = 0; e < 8; e++)
                    acc[e] = fmaf(v, w1[e * 27 + c * 9 + di * 3 + dj], acc[e]);
            }
        }
    }
    float s[8];
#pragma unroll
    for (int e = 0; e < 8; e++) s[e] = 1.0f / (1.0f + __expf(-acc[e]));
    const float inv511 = 1.0f / 511.0f;
    float bx = (float)i * inv511, by = (float)j * inv511;
    float og0 = 0.f, og1 = 0.f, og2 = 0.f;
#pragma unroll
    for (int p = 0; p < 9; p++) {
        float c0, c1;
        if (p < 4)       { c0 = s[2 * p];              c1 = s[2 * p + 1]; }
        else if (p == 4) { c0 = 0.f;                   c1 = 0.f; }
        else             { c0 = 2.0f - s[2 * (p - 5)]; c1 = 2.0f - s[2 * (p - 5) + 1]; }
        float ixf = (bx + c0) * 256.0f + 255.5f;
        float iyf = (by + c1) * 256.0f + 255.5f;
        float ix0f = floorf(ixf), iy0f = floorf(iyf);
        float wx1 = ixf - ix0f, wy1 = iyf - iy0f;
        float wx0 = 1.f - wx1,  wy0 = 1.f - wy1;
        int ix0 = (int)ix0f, iy0 = (int)iy0f;
        float s0 = 0.f, s1 = 0.f, s2 = 0.f;
#pragma unroll
        for (int cy = 0; cy < 2; cy++) {
            int yc = iy0 + cy;
            if (yc < 0 || yc >= HDIM) continue;
            float wy = cy ? wy1 : wy0;
#pragma unroll
            for (int cx = 0; cx < 2; cx++) {
                int xcc = ix0 + cx;
                if (xcc < 0 || xcc >= WDIM) continue;
                float wgt = wy * (cx ? wx1 : wx0);
                size_t base = (size_t)yc * WDIM + xcc;
                s0 = fmaf(xb[base],             wgt, s0);
                s1 = fmaf(xb[PLANE + base],     wgt, s1);
                s2 = fmaf(xb[2 * PLANE + base], wgt, s2);
            }
        }
        int g  = p / 3;
        int k0 = (p % 3) * 3;
        float* og = (g == 0) ? &og0 : (g == 1) ? &og1 : &og2;
        *og = fmaf(s0, w2[g * 9 + k0 + 0], *og);
        *og = fmaf(s1, w2[g * 9 + k0 + 1], *og);
        *og = fmaf(s2, w2[g * 9 + k0 + 2], *og);
    }
    size_t ob = (size_t)(b * 3) * PLANE + (size_t)i * WDIM + j;
    float v0 = og0 + b2[0], v1 = og1 + b2[1], v2 = og2 + b2[2];
    out[ob]             = v0 > 0.f ? v0 : 0.f;
    out[ob + PLANE]     = v1 > 0.f ? v1 : 0.f;
    out[ob + 2 * PLANE] = v2 > 0.f ? v2 : 0.f;
}

extern "C" void kernel_launch(void* const* d_in, const int* in_sizes, int n_in,
                              void* d_out, int out_size, void* d_ws, size_t ws_size,
                              hipStream_t stream) {
    const float* x  = (const float*)d_in[0];
    const float* w1 = (const float*)d_in[1];
    const float* b1 = (const float*)d_in[2];
    const float* w2 = (const float*)d_in[3];
    const float* b2 = (const float*)d_in[4];
    float* out = (float*)d_out;

    int total = BATCH * HDIM * WDIM;                 // 2,097,152
    size_t need = (size_t)total * 8 + 16;            // 16 MiB fp16x4 pack + pad

    if (ws_size >= need) {
        repack_quad<<<8 * PACK_PAIRS, 256, 0, stream>>>(x, (half8v*)d_ws);
        seesaw_v10<<<BATCH * HDIM, 256, 0, stream>>>(x, (const char*)d_ws,
                                                     w1, b1, w2, b2, out);
    } else {
        seesaw_fused_v1<<<total / 256, 256, 0, stream>>>(x, w1, b1, w2, b2, out);
    }
}